// Round 9
// baseline (333.712 us; speedup 1.0000x reference)
//
#include <hip/hip_runtime.h>

#define BSZ_LG 9
#define BSZ 512            // nodes per destination bucket

// ---------- bf16 helpers ----------
__device__ __forceinline__ float bf_lo(unsigned u) { return __uint_as_float(u << 16); }
__device__ __forceinline__ float bf_hi(unsigned u) { return __uint_as_float(u & 0xffff0000u); }
__device__ __forceinline__ float bf1(unsigned short s) { return __uint_as_float(((unsigned)s) << 16); }
__device__ __forceinline__ unsigned short f2bf(float f) {
    unsigned u = __float_as_uint(f);
    u += 0x7fffu + ((u >> 16) & 1u);   // round-to-nearest-even
    return (unsigned short)(u >> 16);
}
__device__ __forceinline__ unsigned pack2(float a, float b) {
    return (unsigned)f2bf(a) | ((unsigned)f2bf(b) << 16);
}

// ---------- merged setup: flags + zeroing (1 launch, 4 blocks) ----------
__global__ void k_flags(const unsigned* __restrict__ x, const int* __restrict__ ei,
                        int* __restrict__ flagf, int* __restrict__ flage,
                        int* __restrict__ bcnt, int* __restrict__ stats) {
    int t = threadIdx.x;
    if (blockIdx.x == 0) {
        int c = 0;
        for (int i = t; i < 1024; i += 256) {
            unsigned e = (x[i] >> 23) & 0xffu;
            if (e >= 96u && e < 160u) c++;
        }
        __shared__ int s;
        if (t == 0) s = 0;
        __syncthreads();
        atomicAdd(&s, c);
        __syncthreads();
        if (t == 0) *flagf = (s > 512) ? 1 : 0;
    } else if (blockIdx.x == 1) {
        int nz = 0;
        for (int i = t; i < 2048; i += 256) nz |= ei[2 * i + 1];
        __shared__ int s2;
        if (t == 0) s2 = 0;
        __syncthreads();
        if (nz) atomicOr(&s2, 1);
        __syncthreads();
        if (t == 0) *flage = (s2 == 0) ? 1 : 0;
    } else if (blockIdx.x == 2) {
        bcnt[t] = 0;
    } else {
        stats[t] = 0;
    }
}

// ---------- merged param convert (1 launch) ----------
struct Cvt6 {
    const void* src[6];
    unsigned short* dst[6];
    int off[7];
};
__global__ void k_cvt6(Cvt6 a, const int* __restrict__ flagf) {
    int i = blockIdx.x * 256 + threadIdx.x;
    if (i >= a.off[6]) return;
    int s = 0;
#pragma unroll
    for (int j = 1; j < 6; ++j) if (i >= a.off[j]) s = j;
    int k = i - a.off[s];
    unsigned short v;
    if (*flagf) v = f2bf(((const float*)a.src[s])[k]);
    else        v = ((const unsigned short*)a.src[s])[k];
    a.dst[s][k] = v;
}

// ================= bucketed CSR build =================
__global__ __launch_bounds__(256) void k_binA(
        const int* __restrict__ ei, const int* __restrict__ flage,
        int* __restrict__ bcnt, int E, int N, int NBUCK) {
    __shared__ int hist[256];
    int t = threadIdx.x;
    hist[t] = 0;
    __syncthreads();
    int st = *flage + 1;
    int base = blockIdx.x * 4096 + t;
#pragma unroll
    for (int i = 0; i < 16; ++i) {
        int e = base + i * 256;
        if (e < E) {
            int r = ei[(size_t)st * e];
            int c = ei[(size_t)st * (E + e)];
            if ((unsigned)r < (unsigned)N && (unsigned)c < (unsigned)N)
                atomicAdd(&hist[c >> BSZ_LG], 1);
        }
    }
    __syncthreads();
    if (t < NBUCK && hist[t] > 0) atomicAdd(&bcnt[t], hist[t]);
}

__global__ void k_bscan(const int* __restrict__ bcnt, int* __restrict__ bofs,
                        int* __restrict__ bcur, int NBUCK) {
    __shared__ int tmp[256];
    int t = threadIdx.x;
    int v = (t < NBUCK) ? bcnt[t] : 0;
    tmp[t] = v; __syncthreads();
    for (int off = 1; off < 256; off <<= 1) {
        int xv = (t >= off) ? tmp[t - off] : 0;
        __syncthreads();
        tmp[t] += xv;
        __syncthreads();
    }
    if (t < NBUCK) {
        int ex = tmp[t] - v;
        bofs[t] = ex;
        bcur[t] = ex;
        if (t == NBUCK - 1) bofs[NBUCK] = tmp[t];
    }
}

__global__ __launch_bounds__(256) void k_binB(
        const int* __restrict__ ei, const int* __restrict__ flage,
        int* __restrict__ bcur, unsigned* __restrict__ bins, int E, int N, int NBUCK) {
    __shared__ int hist[256], hincl[256], hofs[256], loc[256], gbase[256];
    __shared__ unsigned stage[4096];
    __shared__ unsigned char bseg[4096];
    int t = threadIdx.x;
    hist[t] = 0; loc[t] = 0;
    __syncthreads();
    int st = *flage + 1;
    int base = blockIdx.x * 4096 + t;
    int bs[16]; unsigned vs[16];
#pragma unroll
    for (int i = 0; i < 16; ++i) {
        int e = base + i * 256;
        bs[i] = -1; vs[i] = 0;
        if (e < E) {
            int r = ei[(size_t)st * e];
            int c = ei[(size_t)st * (E + e)];
            if ((unsigned)r < (unsigned)N && (unsigned)c < (unsigned)N) {
                bs[i] = c >> BSZ_LG;
                vs[i] = ((unsigned)r << BSZ_LG) | (unsigned)(c & (BSZ - 1));
                atomicAdd(&hist[bs[i]], 1);
            }
        }
    }
    __syncthreads();
    hincl[t] = hist[t];
    __syncthreads();
    for (int off = 1; off < 256; off <<= 1) {
        int xv = (t >= off) ? hincl[t - off] : 0;
        __syncthreads();
        hincl[t] += xv;
        __syncthreads();
    }
    hofs[t] = hincl[t] - hist[t];
    if (t < NBUCK && hist[t] > 0) gbase[t] = atomicAdd(&bcur[t], hist[t]);
    __syncthreads();
#pragma unroll
    for (int i = 0; i < 16; ++i) {
        if (bs[i] >= 0) {
            int l = atomicAdd(&loc[bs[i]], 1);
            int pos = hofs[bs[i]] + l;
            stage[pos] = vs[i];
            bseg[pos] = (unsigned char)bs[i];
        }
    }
    __syncthreads();
    int total = hincl[255];
    for (int j = t; j < total; j += 256) {
        int b = bseg[j];
        bins[gbase[b] + (j - hofs[b])] = stage[j];
    }
}

// Phase C + fused x-prep
__global__ __launch_bounds__(512) void k_csr(
        const unsigned* __restrict__ bins, const int* __restrict__ bofs,
        const void* __restrict__ x, const int* __restrict__ flagf,
        int* __restrict__ csr, int* __restrict__ ofs,
        float* __restrict__ dinv, unsigned* __restrict__ xs32, int N) {
    __shared__ int tmp[BSZ];
    __shared__ int cur[BSZ];
    __shared__ float sdi[BSZ];
    int b = blockIdx.x, t = threadIdx.x;
    int eb = bofs[b], ee = bofs[b + 1];
    tmp[t] = 0;
    __syncthreads();
    for (int p = eb + t; p < ee; p += BSZ)
        atomicAdd(&tmp[bins[p] & (BSZ - 1)], 1);
    __syncthreads();
    int v = tmp[t];
    for (int off = 1; off < BSZ; off <<= 1) {
        int xv = (t >= off) ? tmp[t - off] : 0;
        __syncthreads();
        tmp[t] += xv;
        __syncthreads();
    }
    int incl = tmp[t];
    int excl = incl - v;
    cur[t] = excl;
    float di = rsqrtf((float)(v + 1));
    sdi[t] = di;
    int node = b * BSZ + t;
    if (node < N) {
        ofs[node]  = eb + excl;
        dinv[node] = di;
        if (node == N - 1) ofs[N] = eb + incl;
    }
    __syncthreads();
    for (int p = eb + t; p < ee; p += BSZ) {
        unsigned xx = bins[p];
        int cl = xx & (BSZ - 1);
        int l = atomicAdd(&cur[cl], 1);
        csr[eb + l] = (int)(xx >> BSZ_LG);
    }
    bool f32 = (*flagf != 0);
    int nbase = b * BSZ;
    for (int i = t; i < BSZ * 16; i += BSZ) {
        int nl = i >> 4;
        int n = nbase + nl;
        if (n >= N) break;
        float d2 = sdi[nl];
        float v0, v1, v2, v3;
        if (f32) {
            float4 f = ((const float4*)x)[(size_t)n * 16 + (i & 15)];
            v0 = f.x; v1 = f.y; v2 = f.z; v3 = f.w;
        } else {
            uint2 u = ((const uint2*)x)[(size_t)n * 16 + (i & 15)];
            v0 = bf_lo(u.x); v1 = bf_hi(u.x); v2 = bf_lo(u.y); v3 = bf_hi(u.y);
        }
        uint2 o; o.x = pack2(d2 * v0, d2 * v1); o.y = pack2(d2 * v2, d2 * v3);
        ((uint2*)xs32)[(size_t)n * 16 + (i & 15)] = o;
    }
}
// ======================================================

// ---------- layer-1 aggregation: half-wave per node, uint loads, 8-deep, persistent ----------
__global__ __launch_bounds__(256) void k_agg1(
        const unsigned* __restrict__ xs32, const int* __restrict__ csr,
        const int* __restrict__ ofs, const float* __restrict__ dinv,
        unsigned* __restrict__ s1_32, int N) {
    int sub = threadIdx.x >> 5, lane = threadIdx.x & 31;
    int stride = gridDim.x * 8;
    for (int node = blockIdx.x * 8 + sub; node < N; node += stride) {
        int beg = ofs[node], end = ofs[node + 1];
        unsigned self = xs32[(size_t)node * 32 + lane];
        float a0 = bf_lo(self), a1 = bf_hi(self);
        int p = beg;
        for (; p + 7 < end; p += 8) {
            int r0 = csr[p], r1 = csr[p+1], r2 = csr[p+2], r3 = csr[p+3];
            int r4 = csr[p+4], r5 = csr[p+5], r6 = csr[p+6], r7 = csr[p+7];
            unsigned u0 = xs32[(size_t)r0 * 32 + lane];
            unsigned u1 = xs32[(size_t)r1 * 32 + lane];
            unsigned u2 = xs32[(size_t)r2 * 32 + lane];
            unsigned u3 = xs32[(size_t)r3 * 32 + lane];
            unsigned u4 = xs32[(size_t)r4 * 32 + lane];
            unsigned u5 = xs32[(size_t)r5 * 32 + lane];
            unsigned u6 = xs32[(size_t)r6 * 32 + lane];
            unsigned u7 = xs32[(size_t)r7 * 32 + lane];
            a0 += bf_lo(u0) + bf_lo(u1) + bf_lo(u2) + bf_lo(u3)
                + bf_lo(u4) + bf_lo(u5) + bf_lo(u6) + bf_lo(u7);
            a1 += bf_hi(u0) + bf_hi(u1) + bf_hi(u2) + bf_hi(u3)
                + bf_hi(u4) + bf_hi(u5) + bf_hi(u6) + bf_hi(u7);
        }
        for (; p + 3 < end; p += 4) {
            int r0 = csr[p], r1 = csr[p+1], r2 = csr[p+2], r3 = csr[p+3];
            unsigned u0 = xs32[(size_t)r0 * 32 + lane];
            unsigned u1 = xs32[(size_t)r1 * 32 + lane];
            unsigned u2 = xs32[(size_t)r2 * 32 + lane];
            unsigned u3 = xs32[(size_t)r3 * 32 + lane];
            a0 += bf_lo(u0) + bf_lo(u1) + bf_lo(u2) + bf_lo(u3);
            a1 += bf_hi(u0) + bf_hi(u1) + bf_hi(u2) + bf_hi(u3);
        }
        for (; p < end; ++p) {
            unsigned u = xs32[(size_t)csr[p] * 32 + lane];
            a0 += bf_lo(u); a1 += bf_hi(u);
        }
        float di = dinv[node];
        s1_32[(size_t)node * 32 + lane] = pack2(di * a0, di * a1);
    }
}

// ---------- MFMA GEMM ----------
typedef __attribute__((ext_vector_type(8))) short bf16x8;
typedef __attribute__((ext_vector_type(4))) float f32x4;

template<int K, int OUTMODE>
__global__ __launch_bounds__(256) void k_mgemm(
        const unsigned short* __restrict__ A, const unsigned short* __restrict__ Wg,
        const unsigned short* __restrict__ bias, void* __restrict__ outv,
        const int* __restrict__ flagf, int N) {
    constexpr int KP = K + 8;
    __shared__ __align__(16) unsigned short sA[64 * KP];
    __shared__ __align__(16) unsigned short sW[128 * KP];
    int t = threadIdx.x;
    int n0 = blockIdx.x * 64;

    for (int i = t; i < K * 128; i += 256) {
        int k = i >> 7, n = i & 127;
        sW[n * KP + k] = Wg[i];
    }
    {
        constexpr int rowv = K / 8;
        const uint4* Av = (const uint4*)A;
        for (int i = t; i < 64 * rowv; i += 256) {
            int r = i / rowv, c = i % rowv;
            int node = n0 + r;
            uint4 v = make_uint4(0u, 0u, 0u, 0u);
            if (node < N) v = Av[(size_t)node * rowv + c];
            *(uint4*)&sA[r * KP + c * 8] = v;
        }
    }
    __syncthreads();

    int lane = t & 63, wave = t >> 6, quad = lane >> 4, l16 = lane & 15;
    int mb = wave * 16;

    f32x4 acc[8];
#pragma unroll
    for (int j = 0; j < 8; ++j) acc[j] = (f32x4){0.f, 0.f, 0.f, 0.f};

#pragma unroll
    for (int k0 = 0; k0 < K; k0 += 32) {
        bf16x8 af = *(const bf16x8*)&sA[(mb + l16) * KP + k0 + quad * 8];
#pragma unroll
        for (int tn = 0; tn < 8; ++tn) {
            bf16x8 bfv = *(const bf16x8*)&sW[(tn * 16 + l16) * KP + k0 + quad * 8];
            acc[tn] = __builtin_amdgcn_mfma_f32_16x16x32_bf16(af, bfv, acc[tn], 0, 0, 0);
        }
    }

    bool f32out = (OUTMODE == 1) && (*flagf != 0);
    int nodeb = n0 + mb + quad * 4;
#pragma unroll
    for (int tn = 0; tn < 8; ++tn) {
        float bv = bf1(bias[tn * 16 + l16]);
#pragma unroll
        for (int r = 0; r < 4; ++r) {
            int node = nodeb + r;
            if (node < N) {
                float v = fmaxf(acc[tn][r] + bv, 0.f);
                if (OUTMODE == 1 && f32out)
                    ((float*)outv)[(size_t)node * 128 + tn * 16 + l16] = v;
                else
                    ((unsigned short*)outv)[(size_t)node * 128 + tn * 16 + l16] = f2bf(v);
            }
        }
    }
}

// ---------- BN stats ----------
__global__ __launch_bounds__(256) void k_bnstat(
        const unsigned short* __restrict__ h1, float* __restrict__ stats, int N) {
    __shared__ float sS[1024], sQ[1024];
    int t = threadIdx.x;
    int lane = t & 31, g = t >> 5;
    int f0 = lane * 4;
    float s0=0, s1=0, s2=0, s3=0, q0=0, q1=0, q2=0, q3=0;
    const uint2* h2 = (const uint2*)h1;
    for (int n = blockIdx.x * 8 + g; n < N; n += 2048) {
        uint2 u = h2[(size_t)n * 32 + lane];
        float v0 = bf_lo(u.x), v1 = bf_hi(u.x), v2 = bf_lo(u.y), v3 = bf_hi(u.y);
        s0 += v0; s1 += v1; s2 += v2; s3 += v3;
        q0 = fmaf(v0, v0, q0); q1 = fmaf(v1, v1, q1);
        q2 = fmaf(v2, v2, q2); q3 = fmaf(v3, v3, q3);
    }
    sS[g * 128 + f0 + 0] = s0; sS[g * 128 + f0 + 1] = s1;
    sS[g * 128 + f0 + 2] = s2; sS[g * 128 + f0 + 3] = s3;
    sQ[g * 128 + f0 + 0] = q0; sQ[g * 128 + f0 + 1] = q1;
    sQ[g * 128 + f0 + 2] = q2; sQ[g * 128 + f0 + 3] = q3;
    __syncthreads();
    if (t < 128) {
        float ss = 0, qq = 0;
#pragma unroll
        for (int gg = 0; gg < 8; ++gg) { ss += sS[gg * 128 + t]; qq += sQ[gg * 128 + t]; }
        atomicAdd(&stats[t], ss);
        atomicAdd(&stats[128 + t], qq);
    }
}

// ---------- BN finalize + apply + fold dinv (fused) ----------
__global__ __launch_bounds__(256) void k_bnapply(
        const unsigned short* __restrict__ h1, const float* __restrict__ stats,
        const unsigned short* __restrict__ gamma, const unsigned short* __restrict__ beta,
        const float* __restrict__ dinv, unsigned short* __restrict__ gb,
        float invN, int N) {
    __shared__ float sp[256];
    int t = threadIdx.x;
    if (t < 128) {
        float mean = stats[t] * invN;
        float var = stats[128 + t] * invN - mean * mean;
        if (!(var >= 0.f)) var = 0.f;
        float sc = bf1(gamma[t]) * rsqrtf(var + 1e-5f);
        sp[t] = sc;
        sp[128 + t] = bf1(beta[t]) - mean * sc;
    }
    __syncthreads();
    int idx = blockIdx.x * 256 + t;
    if (idx >= N * 16) return;
    int n = idx >> 4;
    int f0 = (idx & 15) * 8;
    float di = dinv[n];
    uint4 h = *(const uint4*)&h1[(size_t)n * 128 + f0];
    float v0 = di * (sp[f0 + 0] * bf_lo(h.x) + sp[128 + f0 + 0]);
    float v1 = di * (sp[f0 + 1] * bf_hi(h.x) + sp[128 + f0 + 1]);
    float v2 = di * (sp[f0 + 2] * bf_lo(h.y) + sp[128 + f0 + 2]);
    float v3 = di * (sp[f0 + 3] * bf_hi(h.y) + sp[128 + f0 + 3]);
    float v4 = di * (sp[f0 + 4] * bf_lo(h.z) + sp[128 + f0 + 4]);
    float v5 = di * (sp[f0 + 5] * bf_hi(h.z) + sp[128 + f0 + 5]);
    float v6 = di * (sp[f0 + 6] * bf_lo(h.w) + sp[128 + f0 + 6]);
    float v7 = di * (sp[f0 + 7] * bf_hi(h.w) + sp[128 + f0 + 7]);
    uint4 o;
    o.x = pack2(v0, v1); o.y = pack2(v2, v3);
    o.z = pack2(v4, v5); o.w = pack2(v6, v7);
    *(uint4*)&gb[(size_t)n * 128 + f0] = o;
}

// ---------- layer-2 aggregation: half-wave per node, uint2, 8-deep, persistent ----------
__global__ __launch_bounds__(256) void k_agg2(
        const unsigned short* __restrict__ gb, const int* __restrict__ csr,
        const int* __restrict__ ofs, const float* __restrict__ dinv,
        unsigned short* __restrict__ s2, int N) {
    int sub = threadIdx.x >> 5, lane = threadIdx.x & 31;
    const uint2* g2 = (const uint2*)gb;   // row = 32 uint2 (256 B)
    int stride = gridDim.x * 8;
    for (int node = blockIdx.x * 8 + sub; node < N; node += stride) {
        int beg = ofs[node], end = ofs[node + 1];
        uint2 self = g2[(size_t)node * 32 + lane];
        float a0 = bf_lo(self.x), a1 = bf_hi(self.x);
        float a2 = bf_lo(self.y), a3 = bf_hi(self.y);
        int p = beg;
        for (; p + 7 < end; p += 8) {
            int r0 = csr[p], r1 = csr[p+1], r2 = csr[p+2], r3 = csr[p+3];
            int r4 = csr[p+4], r5 = csr[p+5], r6 = csr[p+6], r7 = csr[p+7];
            uint2 u0 = g2[(size_t)r0 * 32 + lane];
            uint2 u1 = g2[(size_t)r1 * 32 + lane];
            uint2 u2 = g2[(size_t)r2 * 32 + lane];
            uint2 u3 = g2[(size_t)r3 * 32 + lane];
            uint2 u4 = g2[(size_t)r4 * 32 + lane];
            uint2 u5 = g2[(size_t)r5 * 32 + lane];
            uint2 u6 = g2[(size_t)r6 * 32 + lane];
            uint2 u7 = g2[(size_t)r7 * 32 + lane];
            a0 += bf_lo(u0.x) + bf_lo(u1.x) + bf_lo(u2.x) + bf_lo(u3.x)
                + bf_lo(u4.x) + bf_lo(u5.x) + bf_lo(u6.x) + bf_lo(u7.x);
            a1 += bf_hi(u0.x) + bf_hi(u1.x) + bf_hi(u2.x) + bf_hi(u3.x)
                + bf_hi(u4.x) + bf_hi(u5.x) + bf_hi(u6.x) + bf_hi(u7.x);
            a2 += bf_lo(u0.y) + bf_lo(u1.y) + bf_lo(u2.y) + bf_lo(u3.y)
                + bf_lo(u4.y) + bf_lo(u5.y) + bf_lo(u6.y) + bf_lo(u7.y);
            a3 += bf_hi(u0.y) + bf_hi(u1.y) + bf_hi(u2.y) + bf_hi(u3.y)
                + bf_hi(u4.y) + bf_hi(u5.y) + bf_hi(u6.y) + bf_hi(u7.y);
        }
        for (; p + 3 < end; p += 4) {
            int r0 = csr[p], r1 = csr[p+1], r2 = csr[p+2], r3 = csr[p+3];
            uint2 u0 = g2[(size_t)r0 * 32 + lane];
            uint2 u1 = g2[(size_t)r1 * 32 + lane];
            uint2 u2 = g2[(size_t)r2 * 32 + lane];
            uint2 u3 = g2[(size_t)r3 * 32 + lane];
            a0 += bf_lo(u0.x) + bf_lo(u1.x) + bf_lo(u2.x) + bf_lo(u3.x);
            a1 += bf_hi(u0.x) + bf_hi(u1.x) + bf_hi(u2.x) + bf_hi(u3.x);
            a2 += bf_lo(u0.y) + bf_lo(u1.y) + bf_lo(u2.y) + bf_lo(u3.y);
            a3 += bf_hi(u0.y) + bf_hi(u1.y) + bf_hi(u2.y) + bf_hi(u3.y);
        }
        for (; p < end; ++p) {
            uint2 u = g2[(size_t)csr[p] * 32 + lane];
            a0 += bf_lo(u.x); a1 += bf_hi(u.x); a2 += bf_lo(u.y); a3 += bf_hi(u.y);
        }
        float di = dinv[node];
        uint2 o; o.x = pack2(di * a0, di * a1); o.y = pack2(di * a2, di * a3);
        ((uint2*)s2)[(size_t)node * 32 + lane] = o;
    }
}

extern "C" void kernel_launch(void* const* d_in, const int* in_sizes, int n_in,
                              void* d_out, int out_size, void* d_ws, size_t ws_size,
                              hipStream_t stream) {
    const int N = in_sizes[0] / 64;   // 100000
    const int E = in_sizes[1] / 2;    // 1600000
    const int nW1 = in_sizes[2], nb1 = in_sizes[3], ngm = in_sizes[4],
              nbt = in_sizes[5], nW2 = in_sizes[6], nb2 = in_sizes[7];
    const int NBUCK = (N + BSZ - 1) >> BSZ_LG;     // 196

    const int* ei = (const int*)d_in[1];

    char* w = (char*)d_ws;
    size_t off = 0;
    auto alloc = [&](size_t bytes) -> void* {
        void* p = w + off;
        off = (off + bytes + 255) & ~(size_t)255;
        return p;
    };
    int*   bcnt   = (int*)alloc(256 * 4);
    int*   bofs   = (int*)alloc(257 * 4);
    int*   bcur   = (int*)alloc(256 * 4);
    int*   flagf  = (int*)alloc(256);
    int*   flage  = (int*)alloc(256);
    int*   ofs    = (int*)alloc(((size_t)N + 1) * 4);
    int*   csr    = (int*)alloc((size_t)E * 4);
    float* dinv   = (float*)alloc((size_t)N * 4);
    float* stats  = (float*)alloc(512 * 4);
    unsigned* xs32 = (unsigned*)alloc((size_t)N * 64 * 2);
    unsigned short* wb = (unsigned short*)alloc((size_t)32768 * 2);
    char* reg1 = (char*)alloc((size_t)N * 64 * 4);      // bins | s1(bf16) | gb
    char* reg2 = (char*)alloc((size_t)N * 128 * 2);     // h1 | s2
    unsigned* bins = (unsigned*)reg1;
    unsigned short* s1 = (unsigned short*)reg1;
    unsigned short* gb = (unsigned short*)reg1;
    unsigned short* h1 = (unsigned short*)reg2;
    unsigned short* s2 = (unsigned short*)reg2;

    unsigned short* W1b = wb;
    unsigned short* b1b = W1b + nW1;
    unsigned short* gmb = b1b + nb1;
    unsigned short* btb = gmb + ngm;
    unsigned short* W2b = btb + nbt;
    unsigned short* b2b = W2b + nW2;

    const int NCH = (E + 4095) / 4096;

    k_flags <<<4, 256, 0, stream>>>((const unsigned*)d_in[0], ei, flagf, flage,
                                    bcnt, (int*)stats);
    Cvt6 ca;
    ca.src[0] = d_in[2]; ca.dst[0] = W1b;
    ca.src[1] = d_in[3]; ca.dst[1] = b1b;
    ca.src[2] = d_in[4]; ca.dst[2] = gmb;
    ca.src[3] = d_in[5]; ca.dst[3] = btb;
    ca.src[4] = d_in[6]; ca.dst[4] = W2b;
    ca.src[5] = d_in[7]; ca.dst[5] = b2b;
    int szs[6] = {nW1, nb1, ngm, nbt, nW2, nb2};
    ca.off[0] = 0;
    for (int i = 0; i < 6; ++i) ca.off[i + 1] = ca.off[i] + szs[i];
    k_cvt6 <<<(ca.off[6] + 255) / 256, 256, 0, stream>>>(ca, flagf);

    k_binA  <<<NCH, 256, 0, stream>>>(ei, flage, bcnt, E, N, NBUCK);
    k_bscan <<<1, 256, 0, stream>>>(bcnt, bofs, bcur, NBUCK);
    k_binB  <<<NCH, 256, 0, stream>>>(ei, flage, bcur, bins, E, N, NBUCK);
    k_csr   <<<NBUCK, BSZ, 0, stream>>>(bins, bofs, d_in[0], flagf,
                                        csr, ofs, dinv, xs32, N);

    k_agg1  <<<1280, 256, 0, stream>>>(xs32, csr, ofs, dinv, (unsigned*)s1, N);
    k_mgemm<64, 0><<<(N + 63) / 64, 256, 0, stream>>>(s1, W1b, b1b, h1, flagf, N);
    k_bnstat<<<256, 256, 0, stream>>>(h1, stats, N);
    k_bnapply<<<((size_t)N * 16 + 255) / 256, 256, 0, stream>>>(
        h1, stats, gmb, btb, dinv, gb, 1.0f / (float)N, N);
    k_agg2  <<<2000, 256, 0, stream>>>(gb, csr, ofs, dinv, s2, N);
    k_mgemm<128, 1><<<(N + 63) / 64, 256, 0, stream>>>(s2, W2b, b2b, d_out, flagf, N);
}

// Round 10
// 319.783 us; speedup vs baseline: 1.0436x; 1.0436x over previous
//
#include <hip/hip_runtime.h>

#define BSZ_LG 9
#define BSZ 512            // nodes per destination bucket

// ---------- bf16 helpers ----------
__device__ __forceinline__ float bf_lo(unsigned u) { return __uint_as_float(u << 16); }
__device__ __forceinline__ float bf_hi(unsigned u) { return __uint_as_float(u & 0xffff0000u); }
__device__ __forceinline__ float bf1(unsigned short s) { return __uint_as_float(((unsigned)s) << 16); }
__device__ __forceinline__ unsigned short f2bf(float f) {
    unsigned u = __float_as_uint(f);
    u += 0x7fffu + ((u >> 16) & 1u);   // round-to-nearest-even
    return (unsigned short)(u >> 16);
}
__device__ __forceinline__ unsigned pack2(float a, float b) {
    return (unsigned)f2bf(a) | ((unsigned)f2bf(b) << 16);
}

// ---------- merged setup: flags + zeroing (1 launch, 4 blocks) ----------
__global__ void k_flags(const unsigned* __restrict__ x, const int* __restrict__ ei,
                        int* __restrict__ flagf, int* __restrict__ flage,
                        int* __restrict__ bcnt, int* __restrict__ stats) {
    int t = threadIdx.x;
    if (blockIdx.x == 0) {
        int c = 0;
        for (int i = t; i < 1024; i += 256) {
            unsigned e = (x[i] >> 23) & 0xffu;
            if (e >= 96u && e < 160u) c++;
        }
        __shared__ int s;
        if (t == 0) s = 0;
        __syncthreads();
        atomicAdd(&s, c);
        __syncthreads();
        if (t == 0) *flagf = (s > 512) ? 1 : 0;
    } else if (blockIdx.x == 1) {
        int nz = 0;
        for (int i = t; i < 2048; i += 256) nz |= ei[2 * i + 1];
        __shared__ int s2;
        if (t == 0) s2 = 0;
        __syncthreads();
        if (nz) atomicOr(&s2, 1);
        __syncthreads();
        if (t == 0) *flage = (s2 == 0) ? 1 : 0;
    } else if (blockIdx.x == 2) {
        bcnt[t] = 0;
    } else {
        stats[t] = 0;
    }
}

// ---------- param convert descriptor ----------
struct Cvt6 {
    const void* src[6];
    unsigned short* dst[6];
    int off[7];
};

// ================= bucketed CSR build (binA merged with param-cvt) =================
__global__ __launch_bounds__(256) void k_binA_cvt(
        const int* __restrict__ ei, const int* __restrict__ flage,
        int* __restrict__ bcnt, int E, int N, int NBUCK,
        Cvt6 a, const int* __restrict__ flagf, int NCH) {
    int t = threadIdx.x;
    if (blockIdx.x >= NCH) {            // param-convert tail blocks (independent work)
        int i = (blockIdx.x - NCH) * 256 + t;
        if (i < a.off[6]) {
            int s = 0;
#pragma unroll
            for (int j = 1; j < 6; ++j) if (i >= a.off[j]) s = j;
            int k = i - a.off[s];
            unsigned short v;
            if (*flagf) v = f2bf(((const float*)a.src[s])[k]);
            else        v = ((const unsigned short*)a.src[s])[k];
            a.dst[s][k] = v;
        }
        return;
    }
    __shared__ int hist[256];
    hist[t] = 0;
    __syncthreads();
    int st = *flage + 1;
    int base = blockIdx.x * 4096 + t;
#pragma unroll
    for (int i = 0; i < 16; ++i) {
        int e = base + i * 256;
        if (e < E) {
            int r = ei[(size_t)st * e];
            int c = ei[(size_t)st * (E + e)];
            if ((unsigned)r < (unsigned)N && (unsigned)c < (unsigned)N)
                atomicAdd(&hist[c >> BSZ_LG], 1);
        }
    }
    __syncthreads();
    if (t < NBUCK && hist[t] > 0) atomicAdd(&bcnt[t], hist[t]);
}

__global__ void k_bscan(const int* __restrict__ bcnt, int* __restrict__ bofs,
                        int* __restrict__ bcur, int NBUCK) {
    __shared__ int tmp[256];
    int t = threadIdx.x;
    int v = (t < NBUCK) ? bcnt[t] : 0;
    tmp[t] = v; __syncthreads();
    for (int off = 1; off < 256; off <<= 1) {
        int xv = (t >= off) ? tmp[t - off] : 0;
        __syncthreads();
        tmp[t] += xv;
        __syncthreads();
    }
    if (t < NBUCK) {
        int ex = tmp[t] - v;
        bofs[t] = ex;
        bcur[t] = ex;
        if (t == NBUCK - 1) bofs[NBUCK] = tmp[t];
    }
}

__global__ __launch_bounds__(256) void k_binB(
        const int* __restrict__ ei, const int* __restrict__ flage,
        int* __restrict__ bcur, unsigned* __restrict__ bins, int E, int N, int NBUCK) {
    __shared__ int hist[256], hincl[256], hofs[256], loc[256], gbase[256];
    __shared__ unsigned stage[4096];
    __shared__ unsigned char bseg[4096];
    int t = threadIdx.x;
    hist[t] = 0; loc[t] = 0;
    __syncthreads();
    int st = *flage + 1;
    int base = blockIdx.x * 4096 + t;
    int bs[16]; unsigned vs[16];
#pragma unroll
    for (int i = 0; i < 16; ++i) {
        int e = base + i * 256;
        bs[i] = -1; vs[i] = 0;
        if (e < E) {
            int r = ei[(size_t)st * e];
            int c = ei[(size_t)st * (E + e)];
            if ((unsigned)r < (unsigned)N && (unsigned)c < (unsigned)N) {
                bs[i] = c >> BSZ_LG;
                vs[i] = ((unsigned)r << BSZ_LG) | (unsigned)(c & (BSZ - 1));
                atomicAdd(&hist[bs[i]], 1);
            }
        }
    }
    __syncthreads();
    hincl[t] = hist[t];
    __syncthreads();
    for (int off = 1; off < 256; off <<= 1) {
        int xv = (t >= off) ? hincl[t - off] : 0;
        __syncthreads();
        hincl[t] += xv;
        __syncthreads();
    }
    hofs[t] = hincl[t] - hist[t];
    if (t < NBUCK && hist[t] > 0) gbase[t] = atomicAdd(&bcur[t], hist[t]);
    __syncthreads();
#pragma unroll
    for (int i = 0; i < 16; ++i) {
        if (bs[i] >= 0) {
            int l = atomicAdd(&loc[bs[i]], 1);
            int pos = hofs[bs[i]] + l;
            stage[pos] = vs[i];
            bseg[pos] = (unsigned char)bs[i];
        }
    }
    __syncthreads();
    int total = hincl[255];
    for (int j = t; j < total; j += 256) {
        int b = bseg[j];
        bins[gbase[b] + (j - hofs[b])] = stage[j];
    }
}

// Phase C + fused x-prep
__global__ __launch_bounds__(512) void k_csr(
        const unsigned* __restrict__ bins, const int* __restrict__ bofs,
        const void* __restrict__ x, const int* __restrict__ flagf,
        int* __restrict__ csr, int* __restrict__ ofs,
        float* __restrict__ dinv, unsigned* __restrict__ xs32, int N) {
    __shared__ int tmp[BSZ];
    __shared__ int cur[BSZ];
    __shared__ float sdi[BSZ];
    int b = blockIdx.x, t = threadIdx.x;
    int eb = bofs[b], ee = bofs[b + 1];
    tmp[t] = 0;
    __syncthreads();
    for (int p = eb + t; p < ee; p += BSZ)
        atomicAdd(&tmp[bins[p] & (BSZ - 1)], 1);
    __syncthreads();
    int v = tmp[t];
    for (int off = 1; off < BSZ; off <<= 1) {
        int xv = (t >= off) ? tmp[t - off] : 0;
        __syncthreads();
        tmp[t] += xv;
        __syncthreads();
    }
    int incl = tmp[t];
    int excl = incl - v;
    cur[t] = excl;
    float di = rsqrtf((float)(v + 1));
    sdi[t] = di;
    int node = b * BSZ + t;
    if (node < N) {
        ofs[node]  = eb + excl;
        dinv[node] = di;
        if (node == N - 1) ofs[N] = eb + incl;
    }
    __syncthreads();
    for (int p = eb + t; p < ee; p += BSZ) {
        unsigned xx = bins[p];
        int cl = xx & (BSZ - 1);
        int l = atomicAdd(&cur[cl], 1);
        csr[eb + l] = (int)(xx >> BSZ_LG);
    }
    bool f32 = (*flagf != 0);
    int nbase = b * BSZ;
    for (int i = t; i < BSZ * 16; i += BSZ) {
        int nl = i >> 4;
        int n = nbase + nl;
        if (n >= N) break;
        float d2 = sdi[nl];
        float v0, v1, v2, v3;
        if (f32) {
            float4 f = ((const float4*)x)[(size_t)n * 16 + (i & 15)];
            v0 = f.x; v1 = f.y; v2 = f.z; v3 = f.w;
        } else {
            uint2 u = ((const uint2*)x)[(size_t)n * 16 + (i & 15)];
            v0 = bf_lo(u.x); v1 = bf_hi(u.x); v2 = bf_lo(u.y); v3 = bf_hi(u.y);
        }
        uint2 o; o.x = pack2(d2 * v0, d2 * v1); o.y = pack2(d2 * v2, d2 * v3);
        ((uint2*)xs32)[(size_t)n * 16 + (i & 15)] = o;
    }
}
// ======================================================

// ---------- layer-1 aggregation: half-wave per node, uint loads, 8-deep (r6-best shape) ----------
__global__ __launch_bounds__(256) void k_agg1(
        const unsigned* __restrict__ xs32, const int* __restrict__ csr,
        const int* __restrict__ ofs, const float* __restrict__ dinv,
        unsigned* __restrict__ s1_32, int N) {
    int sub = threadIdx.x >> 5, lane = threadIdx.x & 31;
    int node = blockIdx.x * 8 + sub;
    if (node >= N) return;
    int beg = ofs[node], end = ofs[node + 1];
    unsigned self = xs32[(size_t)node * 32 + lane];
    float a0 = bf_lo(self), a1 = bf_hi(self);
    int p = beg;
    for (; p + 7 < end; p += 8) {
        int r0 = csr[p], r1 = csr[p+1], r2 = csr[p+2], r3 = csr[p+3];
        int r4 = csr[p+4], r5 = csr[p+5], r6 = csr[p+6], r7 = csr[p+7];
        unsigned u0 = xs32[(size_t)r0 * 32 + lane];
        unsigned u1 = xs32[(size_t)r1 * 32 + lane];
        unsigned u2 = xs32[(size_t)r2 * 32 + lane];
        unsigned u3 = xs32[(size_t)r3 * 32 + lane];
        unsigned u4 = xs32[(size_t)r4 * 32 + lane];
        unsigned u5 = xs32[(size_t)r5 * 32 + lane];
        unsigned u6 = xs32[(size_t)r6 * 32 + lane];
        unsigned u7 = xs32[(size_t)r7 * 32 + lane];
        a0 += bf_lo(u0) + bf_lo(u1) + bf_lo(u2) + bf_lo(u3)
            + bf_lo(u4) + bf_lo(u5) + bf_lo(u6) + bf_lo(u7);
        a1 += bf_hi(u0) + bf_hi(u1) + bf_hi(u2) + bf_hi(u3)
            + bf_hi(u4) + bf_hi(u5) + bf_hi(u6) + bf_hi(u7);
    }
    for (; p + 3 < end; p += 4) {
        int r0 = csr[p], r1 = csr[p+1], r2 = csr[p+2], r3 = csr[p+3];
        unsigned u0 = xs32[(size_t)r0 * 32 + lane];
        unsigned u1 = xs32[(size_t)r1 * 32 + lane];
        unsigned u2 = xs32[(size_t)r2 * 32 + lane];
        unsigned u3 = xs32[(size_t)r3 * 32 + lane];
        a0 += bf_lo(u0) + bf_lo(u1) + bf_lo(u2) + bf_lo(u3);
        a1 += bf_hi(u0) + bf_hi(u1) + bf_hi(u2) + bf_hi(u3);
    }
    for (; p < end; ++p) {
        unsigned u = xs32[(size_t)csr[p] * 32 + lane];
        a0 += bf_lo(u); a1 += bf_hi(u);
    }
    float di = dinv[node];
    s1_32[(size_t)node * 32 + lane] = pack2(di * a0, di * a1);
}

// ---------- MFMA GEMM ----------
typedef __attribute__((ext_vector_type(8))) short bf16x8;
typedef __attribute__((ext_vector_type(4))) float f32x4;

template<int K, int OUTMODE>
__global__ __launch_bounds__(256) void k_mgemm(
        const unsigned short* __restrict__ A, const unsigned short* __restrict__ Wg,
        const unsigned short* __restrict__ bias, void* __restrict__ outv,
        const int* __restrict__ flagf, int N) {
    constexpr int KP = K + 8;
    __shared__ __align__(16) unsigned short sA[64 * KP];
    __shared__ __align__(16) unsigned short sW[128 * KP];
    int t = threadIdx.x;
    int n0 = blockIdx.x * 64;

    for (int i = t; i < K * 128; i += 256) {
        int k = i >> 7, n = i & 127;
        sW[n * KP + k] = Wg[i];
    }
    {
        constexpr int rowv = K / 8;
        const uint4* Av = (const uint4*)A;
        for (int i = t; i < 64 * rowv; i += 256) {
            int r = i / rowv, c = i % rowv;
            int node = n0 + r;
            uint4 v = make_uint4(0u, 0u, 0u, 0u);
            if (node < N) v = Av[(size_t)node * rowv + c];
            *(uint4*)&sA[r * KP + c * 8] = v;
        }
    }
    __syncthreads();

    int lane = t & 63, wave = t >> 6, quad = lane >> 4, l16 = lane & 15;
    int mb = wave * 16;

    f32x4 acc[8];
#pragma unroll
    for (int j = 0; j < 8; ++j) acc[j] = (f32x4){0.f, 0.f, 0.f, 0.f};

#pragma unroll
    for (int k0 = 0; k0 < K; k0 += 32) {
        bf16x8 af = *(const bf16x8*)&sA[(mb + l16) * KP + k0 + quad * 8];
#pragma unroll
        for (int tn = 0; tn < 8; ++tn) {
            bf16x8 bfv = *(const bf16x8*)&sW[(tn * 16 + l16) * KP + k0 + quad * 8];
            acc[tn] = __builtin_amdgcn_mfma_f32_16x16x32_bf16(af, bfv, acc[tn], 0, 0, 0);
        }
    }

    bool f32out = (OUTMODE == 1) && (*flagf != 0);
    int nodeb = n0 + mb + quad * 4;
#pragma unroll
    for (int tn = 0; tn < 8; ++tn) {
        float bv = bf1(bias[tn * 16 + l16]);
#pragma unroll
        for (int r = 0; r < 4; ++r) {
            int node = nodeb + r;
            if (node < N) {
                float v = fmaxf(acc[tn][r] + bv, 0.f);
                if (OUTMODE == 1 && f32out)
                    ((float*)outv)[(size_t)node * 128 + tn * 16 + l16] = v;
                else
                    ((unsigned short*)outv)[(size_t)node * 128 + tn * 16 + l16] = f2bf(v);
            }
        }
    }
}

// ---------- BN stats ----------
__global__ __launch_bounds__(256) void k_bnstat(
        const unsigned short* __restrict__ h1, float* __restrict__ stats, int N) {
    __shared__ float sS[1024], sQ[1024];
    int t = threadIdx.x;
    int lane = t & 31, g = t >> 5;
    int f0 = lane * 4;
    float s0=0, s1=0, s2=0, s3=0, q0=0, q1=0, q2=0, q3=0;
    const uint2* h2 = (const uint2*)h1;
    for (int n = blockIdx.x * 8 + g; n < N; n += 2048) {
        uint2 u = h2[(size_t)n * 32 + lane];
        float v0 = bf_lo(u.x), v1 = bf_hi(u.x), v2 = bf_lo(u.y), v3 = bf_hi(u.y);
        s0 += v0; s1 += v1; s2 += v2; s3 += v3;
        q0 = fmaf(v0, v0, q0); q1 = fmaf(v1, v1, q1);
        q2 = fmaf(v2, v2, q2); q3 = fmaf(v3, v3, q3);
    }
    sS[g * 128 + f0 + 0] = s0; sS[g * 128 + f0 + 1] = s1;
    sS[g * 128 + f0 + 2] = s2; sS[g * 128 + f0 + 3] = s3;
    sQ[g * 128 + f0 + 0] = q0; sQ[g * 128 + f0 + 1] = q1;
    sQ[g * 128 + f0 + 2] = q2; sQ[g * 128 + f0 + 3] = q3;
    __syncthreads();
    if (t < 128) {
        float ss = 0, qq = 0;
#pragma unroll
        for (int gg = 0; gg < 8; ++gg) { ss += sS[gg * 128 + t]; qq += sQ[gg * 128 + t]; }
        atomicAdd(&stats[t], ss);
        atomicAdd(&stats[128 + t], qq);
    }
}

// ---------- BN finalize + apply + fold dinv (fused) ----------
__global__ __launch_bounds__(256) void k_bnapply(
        const unsigned short* __restrict__ h1, const float* __restrict__ stats,
        const unsigned short* __restrict__ gamma, const unsigned short* __restrict__ beta,
        const float* __restrict__ dinv, unsigned short* __restrict__ gb,
        float invN, int N) {
    __shared__ float sp[256];
    int t = threadIdx.x;
    if (t < 128) {
        float mean = stats[t] * invN;
        float var = stats[128 + t] * invN - mean * mean;
        if (!(var >= 0.f)) var = 0.f;
        float sc = bf1(gamma[t]) * rsqrtf(var + 1e-5f);
        sp[t] = sc;
        sp[128 + t] = bf1(beta[t]) - mean * sc;
    }
    __syncthreads();
    int idx = blockIdx.x * 256 + t;
    if (idx >= N * 16) return;
    int n = idx >> 4;
    int f0 = (idx & 15) * 8;
    float di = dinv[n];
    uint4 h = *(const uint4*)&h1[(size_t)n * 128 + f0];
    float v0 = di * (sp[f0 + 0] * bf_lo(h.x) + sp[128 + f0 + 0]);
    float v1 = di * (sp[f0 + 1] * bf_hi(h.x) + sp[128 + f0 + 1]);
    float v2 = di * (sp[f0 + 2] * bf_lo(h.y) + sp[128 + f0 + 2]);
    float v3 = di * (sp[f0 + 3] * bf_hi(h.y) + sp[128 + f0 + 3]);
    float v4 = di * (sp[f0 + 4] * bf_lo(h.z) + sp[128 + f0 + 4]);
    float v5 = di * (sp[f0 + 5] * bf_hi(h.z) + sp[128 + f0 + 5]);
    float v6 = di * (sp[f0 + 6] * bf_lo(h.w) + sp[128 + f0 + 6]);
    float v7 = di * (sp[f0 + 7] * bf_hi(h.w) + sp[128 + f0 + 7]);
    uint4 o;
    o.x = pack2(v0, v1); o.y = pack2(v2, v3);
    o.z = pack2(v4, v5); o.w = pack2(v6, v7);
    *(uint4*)&gb[(size_t)n * 128 + f0] = o;
}

// ---------- layer-2 aggregation: half-wave per node, uint2, 8-deep (r6-best shape) ----------
__global__ __launch_bounds__(256) void k_agg2(
        const unsigned short* __restrict__ gb, const int* __restrict__ csr,
        const int* __restrict__ ofs, const float* __restrict__ dinv,
        unsigned short* __restrict__ s2, int N) {
    int sub = threadIdx.x >> 5, lane = threadIdx.x & 31;
    int node = blockIdx.x * 8 + sub;
    if (node >= N) return;
    const uint2* g2 = (const uint2*)gb;   // row = 32 uint2 (256 B)
    int beg = ofs[node], end = ofs[node + 1];
    uint2 self = g2[(size_t)node * 32 + lane];
    float a0 = bf_lo(self.x), a1 = bf_hi(self.x);
    float a2 = bf_lo(self.y), a3 = bf_hi(self.y);
    int p = beg;
    for (; p + 7 < end; p += 8) {
        int r0 = csr[p], r1 = csr[p+1], r2 = csr[p+2], r3 = csr[p+3];
        int r4 = csr[p+4], r5 = csr[p+5], r6 = csr[p+6], r7 = csr[p+7];
        uint2 u0 = g2[(size_t)r0 * 32 + lane];
        uint2 u1 = g2[(size_t)r1 * 32 + lane];
        uint2 u2 = g2[(size_t)r2 * 32 + lane];
        uint2 u3 = g2[(size_t)r3 * 32 + lane];
        uint2 u4 = g2[(size_t)r4 * 32 + lane];
        uint2 u5 = g2[(size_t)r5 * 32 + lane];
        uint2 u6 = g2[(size_t)r6 * 32 + lane];
        uint2 u7 = g2[(size_t)r7 * 32 + lane];
        a0 += bf_lo(u0.x) + bf_lo(u1.x) + bf_lo(u2.x) + bf_lo(u3.x)
            + bf_lo(u4.x) + bf_lo(u5.x) + bf_lo(u6.x) + bf_lo(u7.x);
        a1 += bf_hi(u0.x) + bf_hi(u1.x) + bf_hi(u2.x) + bf_hi(u3.x)
            + bf_hi(u4.x) + bf_hi(u5.x) + bf_hi(u6.x) + bf_hi(u7.x);
        a2 += bf_lo(u0.y) + bf_lo(u1.y) + bf_lo(u2.y) + bf_lo(u3.y)
            + bf_lo(u4.y) + bf_lo(u5.y) + bf_lo(u6.y) + bf_lo(u7.y);
        a3 += bf_hi(u0.y) + bf_hi(u1.y) + bf_hi(u2.y) + bf_hi(u3.y)
            + bf_hi(u4.y) + bf_hi(u5.y) + bf_hi(u6.y) + bf_hi(u7.y);
    }
    for (; p + 3 < end; p += 4) {
        int r0 = csr[p], r1 = csr[p+1], r2 = csr[p+2], r3 = csr[p+3];
        uint2 u0 = g2[(size_t)r0 * 32 + lane];
        uint2 u1 = g2[(size_t)r1 * 32 + lane];
        uint2 u2 = g2[(size_t)r2 * 32 + lane];
        uint2 u3 = g2[(size_t)r3 * 32 + lane];
        a0 += bf_lo(u0.x) + bf_lo(u1.x) + bf_lo(u2.x) + bf_lo(u3.x);
        a1 += bf_hi(u0.x) + bf_hi(u1.x) + bf_hi(u2.x) + bf_hi(u3.x);
        a2 += bf_lo(u0.y) + bf_lo(u1.y) + bf_lo(u2.y) + bf_lo(u3.y);
        a3 += bf_hi(u0.y) + bf_hi(u1.y) + bf_hi(u2.y) + bf_hi(u3.y);
    }
    for (; p < end; ++p) {
        uint2 u = g2[(size_t)csr[p] * 32 + lane];
        a0 += bf_lo(u.x); a1 += bf_hi(u.x); a2 += bf_lo(u.y); a3 += bf_hi(u.y);
    }
    float di = dinv[node];
    uint2 o; o.x = pack2(di * a0, di * a1); o.y = pack2(di * a2, di * a3);
    ((uint2*)s2)[(size_t)node * 32 + lane] = o;
}

extern "C" void kernel_launch(void* const* d_in, const int* in_sizes, int n_in,
                              void* d_out, int out_size, void* d_ws, size_t ws_size,
                              hipStream_t stream) {
    const int N = in_sizes[0] / 64;   // 100000
    const int E = in_sizes[1] / 2;    // 1600000
    const int nW1 = in_sizes[2], nb1 = in_sizes[3], ngm = in_sizes[4],
              nbt = in_sizes[5], nW2 = in_sizes[6], nb2 = in_sizes[7];
    const int NBUCK = (N + BSZ - 1) >> BSZ_LG;     // 196

    const int* ei = (const int*)d_in[1];

    char* w = (char*)d_ws;
    size_t off = 0;
    auto alloc = [&](size_t bytes) -> void* {
        void* p = w + off;
        off = (off + bytes + 255) & ~(size_t)255;
        return p;
    };
    int*   bcnt   = (int*)alloc(256 * 4);
    int*   bofs   = (int*)alloc(257 * 4);
    int*   bcur   = (int*)alloc(256 * 4);
    int*   flagf  = (int*)alloc(256);
    int*   flage  = (int*)alloc(256);
    int*   ofs    = (int*)alloc(((size_t)N + 1) * 4);
    int*   csr    = (int*)alloc((size_t)E * 4);
    float* dinv   = (float*)alloc((size_t)N * 4);
    float* stats  = (float*)alloc(512 * 4);
    unsigned* xs32 = (unsigned*)alloc((size_t)N * 64 * 2);
    unsigned short* wb = (unsigned short*)alloc((size_t)32768 * 2);
    char* reg1 = (char*)alloc((size_t)N * 64 * 4);      // bins | s1(bf16) | gb
    char* reg2 = (char*)alloc((size_t)N * 128 * 2);     // h1 | s2
    unsigned* bins = (unsigned*)reg1;
    unsigned short* s1 = (unsigned short*)reg1;
    unsigned short* gb = (unsigned short*)reg1;
    unsigned short* h1 = (unsigned short*)reg2;
    unsigned short* s2 = (unsigned short*)reg2;

    unsigned short* W1b = wb;
    unsigned short* b1b = W1b + nW1;
    unsigned short* gmb = b1b + nb1;
    unsigned short* btb = gmb + ngm;
    unsigned short* W2b = btb + nbt;
    unsigned short* b2b = W2b + nW2;

    const int NCH = (E + 4095) / 4096;

    k_flags <<<4, 256, 0, stream>>>((const unsigned*)d_in[0], ei, flagf, flage,
                                    bcnt, (int*)stats);
    Cvt6 ca;
    ca.src[0] = d_in[2]; ca.dst[0] = W1b;
    ca.src[1] = d_in[3]; ca.dst[1] = b1b;
    ca.src[2] = d_in[4]; ca.dst[2] = gmb;
    ca.src[3] = d_in[5]; ca.dst[3] = btb;
    ca.src[4] = d_in[6]; ca.dst[4] = W2b;
    ca.src[5] = d_in[7]; ca.dst[5] = b2b;
    int szs[6] = {nW1, nb1, ngm, nbt, nW2, nb2};
    ca.off[0] = 0;
    for (int i = 0; i < 6; ++i) ca.off[i + 1] = ca.off[i] + szs[i];
    const int CVB = (ca.off[6] + 255) / 256;

    k_binA_cvt <<<NCH + CVB, 256, 0, stream>>>(ei, flage, bcnt, E, N, NBUCK,
                                               ca, flagf, NCH);
    k_bscan <<<1, 256, 0, stream>>>(bcnt, bofs, bcur, NBUCK);
    k_binB  <<<NCH, 256, 0, stream>>>(ei, flage, bcur, bins, E, N, NBUCK);
    k_csr   <<<NBUCK, BSZ, 0, stream>>>(bins, bofs, d_in[0], flagf,
                                        csr, ofs, dinv, xs32, N);

    k_agg1  <<<(N + 7) / 8, 256, 0, stream>>>(xs32, csr, ofs, dinv, (unsigned*)s1, N);
    k_mgemm<64, 0><<<(N + 63) / 64, 256, 0, stream>>>(s1, W1b, b1b, h1, flagf, N);
    k_bnstat<<<256, 256, 0, stream>>>(h1, stats, N);
    k_bnapply<<<((size_t)N * 16 + 255) / 256, 256, 0, stream>>>(
        h1, stats, gmb, btb, dinv, gb, 1.0f / (float)N, N);
    k_agg2  <<<(N + 7) / 8, 256, 0, stream>>>(gb, csr, ofs, dinv, s2, N);
    k_mgemm<128, 1><<<(N + 63) / 64, 256, 0, stream>>>(s2, W2b, b2b, d_out, flagf, N);
}